// Round 6
// baseline (659.545 us; speedup 1.0000x reference)
//
#include <hip/hip_runtime.h>
#include <hip/hip_bf16.h>
#include <math.h>

#define NND 6144
#define NED 12288
static constexpr float EPS_BN = 1e-5f;

// ---------------- ws layout (float offsets) ----------------
#define HN_OFF    0         // [N,32] Hn
#define HE_OFF    196608    // [N,2]
#define ST_OFF    208896    // [64]: sum0[16] sq0[16] | us5[5]
#define Y_OFF     208960    // YT [32,N]
#define T0_OFF    405568    // H [N,32], then Zc0 [E,16]
#define T1_OFF    602176    // ZtT [16,E]
#define Z0_OFF    798784    // [E]
#define Z1_OFF    811072    // [E]
#define U_OFF     823360    // [E]
#define S_OFF     835648    // [E]
#define PP_OFF    847936    // head partials [64][N]

typedef float floatx4 __attribute__((ext_vector_type(4)));

__device__ __forceinline__ float4 ntload4(const float* p) {
  floatx4 v = __builtin_nontemporal_load(reinterpret_cast<const floatx4*>(p));
  return make_float4(v.x, v.y, v.z, v.w);
}
__device__ __forceinline__ float4 ld4(const float* p) {
  return *reinterpret_cast<const float4*>(p);
}

// async global->LDS, 16 B per lane. LDS dest = wave-uniform base + lane*16.
__device__ __forceinline__ void gll16(const float* g, float* l) {
  __builtin_amdgcn_global_load_lds(
      (const __attribute__((address_space(1))) unsigned int*)g,
      (__attribute__((address_space(3))) unsigned int*)l, 16, 0, 0);
}

__global__ void init_ws(float* __restrict__ p, int n) {
  int i = blockIdx.x * blockDim.x + threadIdx.x;
  if (i < n) p[i] = 0.f;
}

// CT[oc, m] = X[m,:] @ W[oc,:] (+bias). One thread per row m, transposed output.
template<int IC, int OC>
__global__ void small_mm_T(const float* __restrict__ X, const float* __restrict__ W,
                           const float* __restrict__ bias, float* __restrict__ CT, int M) {
  int m = blockIdx.x * blockDim.x + threadIdx.x;
  if (m >= M) return;
  float x[IC];
  #pragma unroll
  for (int k = 0; k < IC; k += 4) {
    float4 v = ld4(X + (size_t)m * IC + k);
    x[k] = v.x; x[k+1] = v.y; x[k+2] = v.z; x[k+3] = v.w;
  }
  #pragma unroll
  for (int oc = 0; oc < OC; ++oc) {
    float s = bias ? bias[oc] : 0.f;
    #pragma unroll
    for (int k = 0; k < IC; ++k) s = fmaf(x[k], W[oc * IC + k], s);
    CT[(size_t)oc * M + m] = s;
  }
}

// out[M,NC] = A[M,K] @ YT[NC,K]^T. Counted-vmcnt 2-deep pipeline:
// all loads via global_load_lds (Y panel + A tile), raw s_barrier, manual
// s_waitcnt vmcnt(G) -- prefetch for chunk k+2 stays in flight across barriers.
// block=256 (4 waves). CG col-groups of 16; ROWS=(4/CG)*4 rows per block.
template<int NC, int CG, bool RELU, bool STATS>
__global__ __launch_bounds__(256, 2)
void gemm_pipe(const float* __restrict__ A, const float* __restrict__ YT,
               const float* __restrict__ bias, float* __restrict__ out,
               float* __restrict__ stats, int K) {
  constexpr int RG = 4 / CG;
  constexpr int ROWS = RG * 4;
  constexpr int YR_W = NC / 4;    // Y rows staged per wave
  constexpr int AR_W = ROWS / 4;  // A rows staged per wave
  constexpr int G = YR_W + AR_W;  // global_load_lds per wave per chunk
  __shared__ float Yb[2][NC][256];
  __shared__ float Ab[2][ROWS][256];
  __shared__ float sst[32];

  const int tid = threadIdx.x;
  const int lane = tid & 63;
  const int w = tid >> 6;
  const int cg = w % CG, rg = w / CG;
  const int r0 = blockIdx.x * ROWS;
  const int c0 = cg * 16;

  auto stage = [&](int kb, int b) {
    #pragma unroll
    for (int i = 0; i < YR_W; ++i) {
      const int yr = w * YR_W + i;
      gll16(YT + (size_t)yr * K + kb + lane * 4, &Yb[b][yr][0]);
    }
    #pragma unroll
    for (int i = 0; i < AR_W; ++i) {
      const int ar = w * AR_W + i;
      gll16(A + (size_t)(r0 + ar) * K + kb + lane * 4, &Ab[b][ar][0]);
    }
  };

  float acc[4][16];
  #pragma unroll
  for (int r = 0; r < 4; ++r)
    #pragma unroll
    for (int c = 0; c < 16; ++c) acc[r][c] = 0.f;

  // prologue: 2 chunks in flight, wait only for the first
  stage(0, 0);
  stage(256, 1);
  asm volatile("s_waitcnt vmcnt(%0)" :: "n"(G) : "memory");
  __builtin_amdgcn_sched_barrier(0);
  __builtin_amdgcn_s_barrier();

  int cur = 0;
  for (int kb = 0; kb < K; kb += 256) {
    // ---- compute on buf[cur] (LDS only; prefetch in flight) ----
    float4 av[4];
    #pragma unroll
    for (int r = 0; r < 4; ++r)
      av[r] = *reinterpret_cast<const float4*>(&Ab[cur][rg * 4 + r][lane * 4]);
    #pragma unroll
    for (int c = 0; c < 16; ++c) {
      const float4 y = *reinterpret_cast<const float4*>(&Yb[cur][c0 + c][lane * 4]);
      #pragma unroll
      for (int r = 0; r < 4; ++r) {
        acc[r][c] = fmaf(av[r].x, y.x, acc[r][c]);
        acc[r][c] = fmaf(av[r].y, y.y, acc[r][c]);
        acc[r][c] = fmaf(av[r].z, y.z, acc[r][c]);
        acc[r][c] = fmaf(av[r].w, y.w, acc[r][c]);
      }
    }
    // all waves done reading buf[cur] -> safe to overwrite
    __builtin_amdgcn_s_barrier();
    if (kb + 512 < K) {
      stage(kb + 512, cur);
      asm volatile("s_waitcnt vmcnt(%0)" :: "n"(G) : "memory"); // chunk kb+256 done
    } else {
      asm volatile("s_waitcnt vmcnt(0)" ::: "memory");
    }
    __builtin_amdgcn_sched_barrier(0);
    __builtin_amdgcn_s_barrier();  // buf[cur^1] fully populated for everyone
    cur ^= 1;
  }

  // Compact cross-lane reduce: 64 values x 64 lanes -> lane l holds value l.
  float wv[64];
  #pragma unroll
  for (int r = 0; r < 4; ++r)
    #pragma unroll
    for (int c = 0; c < 16; ++c) wv[r * 16 + c] = acc[r][c];
  #pragma unroll
  for (int b = 5; b >= 0; --b) {
    const int m = 1 << b;
    const bool hi = (lane & m) != 0;
    #pragma unroll
    for (int i = 0; i < (1 << b); ++i) {
      float a  = wv[i];
      float bb = wv[i + (1 << b)];
      float send = hi ? a : bb;
      float recv = __shfl_xor(send, m, 64);
      wv[i] = (hi ? bb : a) + recv;
    }
  }

  const int rsel = lane >> 4, csel = lane & 15;
  const int rw = rg * 4;  // row-group base within block
  float v = wv[0] + (bias ? bias[c0 + csel] : 0.f);
  if (RELU) v = fmaxf(v, 0.f);
  out[(size_t)(r0 + rw + rsel) * NC + c0 + csel] = v;

  if (STATS) {
    if (tid < 32) sst[tid] = 0.f;
    __syncthreads();
    float sv = v, qv = v * v;
    sv += __shfl_xor(sv, 16, 64); sv += __shfl_xor(sv, 32, 64);
    qv += __shfl_xor(qv, 16, 64); qv += __shfl_xor(qv, 32, 64);
    if (lane < 16) { atomicAdd(&sst[csel], sv); atomicAdd(&sst[16 + csel], qv); }
    __syncthreads();
    if (tid < 32) atomicAdd(stats + tid, sst[tid]);
  }
}

// Row-dot pass, chunk 512, FULL depth-1 prefetch (matrix AND vectors) so the
// compiler's pre-FMA waitcnt is vmcnt(#newer), keeping HBM prefetch in flight.
// MODE 0: o1[row]=M·za, o2[row]=rowsum.  MODE 1: o1[2row]=M·za, o1[2row+1]=M·zb.
// REV: process rows in reverse order (consume L3-resident tail first).
template<int MODE, bool REV>
__global__ __launch_bounds__(256)
void rowpass(const float* __restrict__ Mt, const float* __restrict__ za,
             const float* __restrict__ zb, float* __restrict__ o1,
             float* __restrict__ o2, int K) {
  const int lane = threadIdx.x & 63;
  const int blk = REV ? (gridDim.x - 1 - blockIdx.x) : blockIdx.x;
  const int row = blk * 4 + (threadIdx.x >> 6);
  const float* mp = Mt + (size_t)row * K;
  float accA = 0.f, accB = 0.f;
  float4 a0 = ntload4(mp + lane * 4);
  float4 a1 = ntload4(mp + 256 + lane * 4);
  float4 z0 = ld4(za + lane * 4);
  float4 z1 = ld4(za + 256 + lane * 4);
  float4 y0, y1;
  if (MODE == 1) { y0 = ld4(zb + lane * 4); y1 = ld4(zb + 256 + lane * 4); }
  for (int kb = 0; kb < K; kb += 512) {
    const int k = kb + lane * 4;
    const bool more = (kb + 512) < K;
    float4 na0, na1, nz0, nz1, ny0, ny1;
    if (more) {
      na0 = ntload4(mp + k + 512);
      na1 = ntload4(mp + k + 768);
      nz0 = ld4(za + k + 512);
      nz1 = ld4(za + k + 768);
      if (MODE == 1) { ny0 = ld4(zb + k + 512); ny1 = ld4(zb + k + 768); }
    }
    if (MODE == 0) {
      accA += a0.x*z0.x + a0.y*z0.y + a0.z*z0.z + a0.w*z0.w
            + a1.x*z1.x + a1.y*z1.y + a1.z*z1.z + a1.w*z1.w;
      accB += a0.x + a0.y + a0.z + a0.w + a1.x + a1.y + a1.z + a1.w;
    } else {
      accA += a0.x*z0.x + a0.y*z0.y + a0.z*z0.z + a0.w*z0.w
            + a1.x*z1.x + a1.y*z1.y + a1.z*z1.z + a1.w*z1.w;
      accB += a0.x*y0.x + a0.y*y0.y + a0.z*y0.z + a0.w*y0.w
            + a1.x*y1.x + a1.y*y1.y + a1.z*y1.z + a1.w*y1.w;
    }
    if (more) {
      a0 = na0; a1 = na1; z0 = nz0; z1 = nz1;
      if (MODE == 1) { y0 = ny0; y1 = ny1; }
    }
  }
  #pragma unroll
  for (int m = 1; m < 64; m <<= 1) {
    accA += __shfl_xor(accA, m, 64);
    accB += __shfl_xor(accB, m, 64);
  }
  if (lane == 0) {
    if (MODE == 0) { o1[row] = accA; o2[row] = accB; }
    else { o1[row * 2] = accA; o1[row * 2 + 1] = accB; }
  }
}

// Z[e] = relu(max_c(g[c]*(x-m)*rsqrt(v+eps)+beta[c]))  -- layer-0 BN+max
__global__ void bn_max(const float* __restrict__ Zc, const float* __restrict__ stats,
                       const float* __restrict__ g, const float* __restrict__ beta,
                       float* __restrict__ Z, int E) {
  const int e = blockIdx.x * blockDim.x + threadIdx.x;
  if (e >= E) return;
  const float invE = 1.f / (float)E;
  float best = -3.4e38f;
  #pragma unroll
  for (int c = 0; c < 16; ++c) {
    float m = stats[c] * invE;
    float var = stats[16 + c] * invE - m * m;
    float sc = g[c] * rsqrtf(var + EPS_BN);
    float sh = beta[c] - m * sc;
    float x = Zc[(size_t)e * 16 + c];
    best = fmaxf(best, fmaf(x, sc, sh));
  }
  Z[e] = fmaxf(best, 0.f);
}

// Layer-1 collapsed BN stats: st5 = [Σu, Σs, Σu², Σs², Σus]
__global__ void us_stats(const float* __restrict__ u, const float* __restrict__ s,
                         float* __restrict__ st5) {
  const int e = blockIdx.x * 256 + threadIdx.x;
  const int lane = threadIdx.x & 63;
  const int w = threadIdx.x >> 6;
  const float uu = u[e], ss = s[e];
  float v[5] = {uu, ss, uu * uu, ss * ss, uu * ss};
  #pragma unroll
  for (int i = 0; i < 5; ++i)
    #pragma unroll
    for (int m = 1; m < 64; m <<= 1) v[i] += __shfl_xor(v[i], m, 64);
  __shared__ float red[4][5];
  if (lane == 0) {
    #pragma unroll
    for (int i = 0; i < 5; ++i) red[w][i] = v[i];
  }
  __syncthreads();
  if (threadIdx.x < 5) {
    float t = red[0][threadIdx.x] + red[1][threadIdx.x] + red[2][threadIdx.x] + red[3][threadIdx.x];
    atomicAdd(st5 + threadIdx.x, t);
  }
}

// Z1 directly from (u,s): Zc1[e,c] = W1[c]u + b1[c]s, BN via collapsed stats.
__global__ void z1_from_us(const float* __restrict__ u, const float* __restrict__ s,
                           const float* __restrict__ st5,
                           const float* __restrict__ W1, const float* __restrict__ b1,
                           const float* __restrict__ g, const float* __restrict__ beta,
                           float* __restrict__ Z1, int E) {
  const int e = blockIdx.x * blockDim.x + threadIdx.x;
  if (e >= E) return;
  const float invE = 1.f / (float)E;
  const float Su = st5[0], Ss = st5[1], Suu = st5[2], Sss = st5[3], Sus = st5[4];
  const float uu = u[e], ssv = s[e];
  float best = -3.4e38f;
  #pragma unroll
  for (int c = 0; c < 16; ++c) {
    const float wc = W1[c], bc = b1[c];
    const float mean = (wc * Su + bc * Ss) * invE;
    const float ex2 = (wc * wc * Suu + 2.f * wc * bc * Sus + bc * bc * Sss) * invE;
    const float var = ex2 - mean * mean;
    const float sc = g[c] * rsqrtf(var + EPS_BN);
    const float sh = beta[c] - mean * sc;
    best = fmaxf(best, fmaf(wc * uu + bc * ssv, sc, sh));
  }
  Z1[e] = fmaxf(best, 0.f);
}

// prepart[jb][n] = sum_{j in chunk jb} relu(Hcat[n]·fc1W[j] + fc1b[j]) * fc2W[j]
__global__ __launch_bounds__(256, 2)
void head(const float* __restrict__ Hn, const float* __restrict__ he,
          const float* __restrict__ W1, const float* __restrict__ b1,
          const float* __restrict__ w2, float* __restrict__ prepart) {
  const int t = threadIdx.x;
  const int nb = blockIdx.x;      // 8 blocks of 768 rows
  const int jb = blockIdx.y;      // 64 chunks of 192 j
  int n[3];
  float h[3][34];
  float acc[3] = {0.f, 0.f, 0.f};
  #pragma unroll
  for (int i = 0; i < 3; ++i) {
    n[i] = nb * 768 + i * 256 + t;
    #pragma unroll
    for (int k = 0; k < 32; k += 4) {
      float4 v = ld4(Hn + (size_t)n[i] * 32 + k);
      h[i][k] = v.x; h[i][k+1] = v.y; h[i][k+2] = v.z; h[i][k+3] = v.w;
    }
    float2 e2 = *reinterpret_cast<const float2*>(he + n[i] * 2);
    h[i][32] = e2.x;
    h[i][33] = e2.y;
  }
  const int j0 = jb * 192;
  for (int j = j0; j < j0 + 192; ++j) {
    const float* wp = W1 + (size_t)j * 34;
    const float bj = b1[j], vj = w2[j];
    float s0 = bj, s1 = bj, s2 = bj;
    #pragma unroll
    for (int k = 0; k < 34; ++k) {
      const float wk = wp[k];
      s0 = fmaf(h[0][k], wk, s0);
      s1 = fmaf(h[1][k], wk, s1);
      s2 = fmaf(h[2][k], wk, s2);
    }
    acc[0] += fmaxf(s0, 0.f) * vj;
    acc[1] += fmaxf(s1, 0.f) * vj;
    acc[2] += fmaxf(s2, 0.f) * vj;
  }
  #pragma unroll
  for (int i = 0; i < 3; ++i) prepart[(size_t)jb * NND + n[i]] = acc[i];
}

__global__ void final_k(const float* __restrict__ pp, const float* __restrict__ b2,
                        float* __restrict__ out, int Nn) {
  const int i = blockIdx.x * blockDim.x + threadIdx.x;
  if (i >= Nn) return;
  float s = 0.f;
  #pragma unroll
  for (int j = 0; j < 64; ++j) s += pp[(size_t)j * NND + i];
  out[i] = 1.f / (1.f + expf(-(s + b2[0])));
}

extern "C" void kernel_launch(void* const* d_in, const int* in_sizes, int n_in,
                              void* d_out, int out_size, void* d_ws, size_t ws_size,
                              hipStream_t stream) {
  const float* X_n   = (const float*)d_in[0];
  const float* X_e   = (const float*)d_in[1];
  const float* A     = (const float*)d_in[2];
  const float* L1    = (const float*)d_in[3];
  const float* B1    = (const float*)d_in[4];
  const float* gW0   = (const float*)d_in[5];
  const float* gb0   = (const float*)d_in[6];
  const float* gW1   = (const float*)d_in[7];
  const float* gb1   = (const float*)d_in[8];
  const float* tW0   = (const float*)d_in[9];
  const float* tb0   = (const float*)d_in[10];
  const float* bng0  = (const float*)d_in[11];
  const float* bnb0  = (const float*)d_in[12];
  const float* tW1   = (const float*)d_in[13];
  const float* tb1   = (const float*)d_in[14];
  const float* bng1  = (const float*)d_in[15];
  const float* bnb1  = (const float*)d_in[16];
  const float* fc1W  = (const float*)d_in[17];
  const float* fc1b  = (const float*)d_in[18];
  const float* fc2W  = (const float*)d_in[19];
  const float* fc2b  = (const float*)d_in[20];

  float* ws   = (float*)d_ws;
  float* Hn   = ws + HN_OFF;
  float* he   = ws + HE_OFF;
  float* st   = ws + ST_OFF;
  float* Y    = ws + Y_OFF;
  float* T0   = ws + T0_OFF;
  float* T1   = ws + T1_OFF;
  float* Z0   = ws + Z0_OFF;
  float* Z1   = ws + Z1_OFF;
  float* u    = ws + U_OFF;
  float* s    = ws + S_OFF;
  float* pp   = ws + PP_OFF;
  float* out  = (float*)d_out;

  // zero the atomic stats area (64 floats) every call
  init_ws<<<1, 64, 0, stream>>>(st, 64);

  // ---- GNN (A allocates L2/L3: 2nd pass hits Infinity Cache) ----
  small_mm_T<32, 32><<<24, 256, 0, stream>>>(X_n, gW0, nullptr, Y, NND);          // Y0T
  gemm_pipe<32, 2, true, false><<<768, 256, 0, stream>>>(A, Y, gb0, T0, nullptr, NND);
  small_mm_T<32, 32><<<24, 256, 0, stream>>>(T0, gW1, nullptr, Y, NND);           // Y1T
  gemm_pipe<32, 2, true, false><<<768, 256, 0, stream>>>(A, Y, gb1, Hn, nullptr, NND);

  // ---- HoSC layer 0 (stats fused; L1 tail allocates L3 for reuse below) ----
  small_mm_T<16, 16><<<48, 256, 0, stream>>>(X_e, tW0, tb0, T1, NED);             // Zt0T
  gemm_pipe<16, 1, false, true><<<768, 256, 0, stream>>>(L1, T1, nullptr, T0, st, NED);
  bn_max<<<48, 256, 0, stream>>>(T0, st, bng0, bnb0, Z0, NED);

  // ---- HoSC layer 1 (rank-1 collapse; REVERSE order: eat the L3 tail first) ----
  rowpass<0, true><<<3072, 256, 0, stream>>>(L1, Z0, nullptr, u, s, NED);
  us_stats<<<48, 256, 0, stream>>>(u, s, st + 32);
  z1_from_us<<<48, 256, 0, stream>>>(u, s, st + 32, tW1, tb1, bng1, bnb1, Z1, NED);

  // ---- H_e = B1 @ [Z0 Z1] ----
  rowpass<1, false><<<1536, 256, 0, stream>>>(B1, Z0, Z1, he, nullptr, NED);

  // ---- head (no atomics: per-jb partials, then reduce) ----
  head<<<dim3(8, 64), 256, 0, stream>>>(Hn, he, fc1W, fc1b, fc2W, pp);
  final_k<<<24, 256, 0, stream>>>(pp, fc2b, out, NND);
}